// Round 8
// baseline (306.953 us; speedup 1.0000x reference)
//
#include <hip/hip_runtime.h>

#define BATCH  16
#define NPRED  25200
#define NCLS   80
#define CDIM   85
#define TOPK   4096
#define NBUCK  4096
#define MAXDET 1000
#define CONF_T 0.25f
#define IOU_T  0.45f
#define MAXWH  7680.0f
#define ORD_BASE 0xBE800000u   // ord(0.25f); valid score s>0.25 <=> ord > ORD_BASE

typedef unsigned long long u64;
typedef unsigned int u32;
typedef unsigned short u16;
typedef unsigned char u8;

__device__ __forceinline__ u64 umax64(u64 a, u64 b) { return a > b ? a : b; }
__device__ __forceinline__ u64 umin64(u64 a, u64 b) { return a < b ? a : b; }

__device__ __forceinline__ void cx_u64(u64* a, int i, int p, bool desc) {
    u64 x = a[i], y = a[p];
    if (desc ? (x < y) : (x > y)) { a[i] = y; a[p] = x; }
}

// ---------------- hybrid bitonic sort: 1024 threads × 4 regs, LDS only for j>=256 ----

__device__ void hybrid_sort4096_desc(u64 r[4], u64* a) {
    const int tid = threadIdx.x;
    for (int k = 2; k <= 4096; k <<= 1) {
        if (k >= 512) {                      // LDS stages: j = min(k/2,2048) .. 256
            int jmax = (k >> 1) > 2048 ? 2048 : (k >> 1);
#pragma unroll
            for (int e = 0; e < 4; ++e) a[4 * tid + e] = r[e];
            __syncthreads();
            for (int j = jmax; j >= 256; j >>= 1) {
#pragma unroll
                for (int t2 = 0; t2 < 2; ++t2) {
                    int q = (t2 << 10) | tid;
                    int i = ((q & ~(j - 1)) << 1) | (q & (j - 1));
                    cx_u64(a, i, i | j, (i & k) == 0);
                }
                __syncthreads();
            }
#pragma unroll
            for (int e = 0; e < 4; ++e) r[e] = a[4 * tid + e];
            __syncthreads();
        }
        {                                    // shuffle stages: j = min(k/2,128) .. 4
            int jstart = (k >> 1) > 128 ? 128 : (k >> 1);
            bool desc = (((4 * tid) & k) == 0);
            for (int j = jstart; j >= 4; j >>= 1) {
                int m = j >> 2;
                bool take_max = (((tid & m) == 0) == desc);
#pragma unroll
                for (int e = 0; e < 4; ++e) {
                    u64 v = __shfl_xor(r[e], m, 64);
                    r[e] = take_max ? umax64(r[e], v) : umin64(r[e], v);
                }
            }
        }
        if (k >= 4) {                        // j=2
            bool desc = (((4 * tid) & k) == 0);
            u64 x0 = r[0], x2 = r[2];
            r[0] = desc ? umax64(x0, x2) : umin64(x0, x2);
            r[2] = desc ? umin64(x0, x2) : umax64(x0, x2);
            u64 x1 = r[1], x3 = r[3];
            r[1] = desc ? umax64(x1, x3) : umin64(x1, x3);
            r[3] = desc ? umin64(x1, x3) : umax64(x1, x3);
        }
        {                                    // j=1
            bool d01 = (((4 * tid + 0) & k) == 0);
            bool d23 = (((4 * tid + 2) & k) == 0);
            u64 x0 = r[0], x1 = r[1];
            r[0] = d01 ? umax64(x0, x1) : umin64(x0, x1);
            r[1] = d01 ? umin64(x0, x1) : umax64(x0, x1);
            u64 x2 = r[2], x3 = r[3];
            r[2] = d23 ? umax64(x2, x3) : umin64(x2, x3);
            r[3] = d23 ? umin64(x2, x3) : umax64(x2, x3);
        }
    }
}

// full desc sort of 256 u64 held in wave 0 (4 regs/lane), zero barriers
__device__ void wave_sort256_desc(u64 r[4]) {
    const int lane = threadIdx.x & 63;
    for (int k = 2; k <= 256; k <<= 1) {
        int jstart = (k >> 1) > 128 ? 128 : (k >> 1);
        bool desc = (((4 * lane) & k) == 0);
        for (int j = jstart; j >= 4; j >>= 1) {
            int m = j >> 2;
            bool take_max = (((lane & m) == 0) == desc);
#pragma unroll
            for (int e = 0; e < 4; ++e) {
                u64 v = __shfl_xor(r[e], m, 64);
                r[e] = take_max ? umax64(r[e], v) : umin64(r[e], v);
            }
        }
        if (k >= 4) {
            u64 x0 = r[0], x2 = r[2];
            r[0] = desc ? umax64(x0, x2) : umin64(x0, x2);
            r[2] = desc ? umin64(x0, x2) : umax64(x0, x2);
            u64 x1 = r[1], x3 = r[3];
            r[1] = desc ? umax64(x1, x3) : umin64(x1, x3);
            r[3] = desc ? umin64(x1, x3) : umax64(x1, x3);
        }
        {
            bool d01 = (((4 * lane + 0) & k) == 0);
            bool d23 = (((4 * lane + 2) & k) == 0);
            u64 x0 = r[0], x1 = r[1];
            r[0] = d01 ? umax64(x0, x1) : umin64(x0, x1);
            r[1] = d01 ? umin64(x0, x1) : umax64(x0, x1);
            u64 x2 = r[2], x3 = r[3];
            r[2] = d23 ? umax64(x2, x3) : umin64(x2, x3);
            r[3] = d23 ? umin64(x2, x3) : umax64(x2, x3);
        }
    }
}

// ---------------- K1: score / argmax / key (16 lanes per row, merged loads) ----------------
// key = ord(score)<<32 | (32767-n)<<7 | cls   (desc sort == stable argsort(-s))

__global__ __launch_bounds__(256) void k1_score(const float* __restrict__ pred,
                                                u64* __restrict__ keys) {
    const int lane = threadIdx.x & 63;
    const int l16 = lane & 15;
    const long long gw = (long long)blockIdx.x * 4 + (threadIdx.x >> 6);
    const long long rowIdx = gw * 4 + (lane >> 4);       // global row in [0, BATCH*NPRED)
    const float* row = pred + rowIdx * CDIM;
    float obj = row[4];
    // classes 0..63: 4 consecutive floats per lane (compiler merges to dwordx4)
    float v0 = row[5 + 4 * l16 + 0];
    float v1 = row[5 + 4 * l16 + 1];
    float v2 = row[5 + 4 * l16 + 2];
    float v3 = row[5 + 4 * l16 + 3];
    float v4 = row[69 + l16];                            // classes 64..79
    u64 m = 0ull;
    {
        int c = 4 * l16;
        float s0 = v0 * obj;                             // reference order: product then max
        u64 mk = ((u64)(__float_as_uint(s0) | 0x80000000u) << 32) | (u64)(u32)(NCLS - 1 - c);
        m = mk;
        float s1 = v1 * obj;
        mk = ((u64)(__float_as_uint(s1) | 0x80000000u) << 32) | (u64)(u32)(NCLS - 1 - (c + 1));
        if (mk > m) m = mk;
        float s2 = v2 * obj;
        mk = ((u64)(__float_as_uint(s2) | 0x80000000u) << 32) | (u64)(u32)(NCLS - 1 - (c + 2));
        if (mk > m) m = mk;
        float s3 = v3 * obj;
        mk = ((u64)(__float_as_uint(s3) | 0x80000000u) << 32) | (u64)(u32)(NCLS - 1 - (c + 3));
        if (mk > m) m = mk;
        float s4 = v4 * obj;
        mk = ((u64)(__float_as_uint(s4) | 0x80000000u) << 32) | (u64)(u32)(NCLS - 1 - (64 + l16));
        if (mk > m) m = mk;
    }
#pragma unroll
    for (int o = 8; o > 0; o >>= 1) {
        u64 other = __shfl_xor(m, o, 64);                // reduce within 16-lane group
        if (other > m) m = other;
    }
    if (l16 == 0) {
        const int b = (int)(rowIdx / NPRED);
        const int n = (int)(rowIdx - (long long)b * NPRED);
        float best = __uint_as_float((u32)(m >> 32) & 0x7FFFFFFFu);
        float s = (best > CONF_T) ? best : -1.0f;
        u32 u = __float_as_uint(s);
        u32 ord = (u & 0x80000000u) ? ~u : (u | 0x80000000u);
        keys[rowIdx] = ((u64)ord << 32) | ((u64)(u32)(32767 - n) << 7) |
                       (u64)(u32)((NCLS - 1) - (int)(m & 0x7Fu));
    }
}

// ---------------- K2cs: LDS-hist threshold + compact + sort + build + gather ----------------
// One block per batch. Produces: topSorted, ob, segIdx, count, startg; zeroes keep/gsupp.

__global__ __launch_bounds__(1024) void k2cs(const float* __restrict__ pred,
                                             const u64* __restrict__ keys,
                                             u64* __restrict__ topSorted,
                                             float4* __restrict__ ob,
                                             u16* __restrict__ segIdx,
                                             u32* __restrict__ count,
                                             u32* __restrict__ startg,
                                             u8* __restrict__ keep,
                                             u8* __restrict__ gsupp) {
    __shared__ u64 arena[4096];         // 32 KB sort arena / sorted keys
    __shared__ u64 side[1024];          // bucket-T members
    __shared__ u32 lhist[NBUCK];        // 16 KB
    __shared__ u8 clsb[4096];
    __shared__ u32 cnt[NCLS];
    __shared__ u32 startsh[NCLS];
    __shared__ u32 wsum[16];
    __shared__ int sh_T, sh_C1, sh_R, c1pos, sidepos;
    const int b = blockIdx.x;
    const int tid = threadIdx.x;
    const int lane = tid & 63;
    const int wid = tid >> 6;
    const u64* kb = keys + (long long)b * NPRED;

    // --- phase 0: zero LDS ---
    for (int i = tid; i < NBUCK; i += 1024) lhist[i] = 0u;
    if (tid < NCLS) cnt[tid] = 0u;
    __syncthreads();

    // --- phase 1: histogram from keys ---
    for (int n = tid; n < NPRED; n += 1024) {
        u32 hi = (u32)(kb[n] >> 32);
        if (hi > ORD_BASE) atomicAdd(&lhist[(hi - ORD_BASE - 1u) >> 12], 1u);
    }
    __syncthreads();

    // --- phase 2: threshold scan (descending bucket order) ---
    u32 h[4];
    u32 tsum = 0;
#pragma unroll
    for (int e = 0; e < 4; ++e) {
        h[e] = lhist[NBUCK - 1 - (4 * tid + e)];
        tsum += h[e];
    }
    u32 inc = tsum;
    for (int o = 1; o < 64; o <<= 1) {
        u32 v = __shfl_up(inc, o, 64);
        if (lane >= o) inc += v;
    }
    if (lane == 63) wsum[wid] = inc;
    __syncthreads();
    if (tid == 0) {
        u32 run = 0;
        for (int i = 0; i < 16; ++i) { u32 t = wsum[i]; wsum[i] = run; run += t; }
        sh_T = -1; sh_C1 = (int)run; sh_R = 0;           // defaults: < 4096 valid total
        c1pos = 0; sidepos = 0;
    }
    __syncthreads();
    {
        u32 cum = wsum[wid] + (inc - tsum);              // exclusive prefix before this thread
#pragma unroll
        for (int e = 0; e < 4; ++e) {
            if (h[e] > 0 && cum < (u32)TOPK && cum + h[e] >= (u32)TOPK) {
                sh_T = NBUCK - 1 - (4 * tid + e);        // unique crossing
                sh_C1 = (int)cum;
                sh_R = TOPK - (int)cum;
            }
            cum += h[e];
        }
    }
    __syncthreads();
    const int T = sh_T, C1 = sh_C1, R = sh_R;

    // --- phase 3: zero arena, compact ---
    for (int i = tid; i < 4096; i += 1024) arena[i] = 0ull;
    side[tid] = 0ull;
    __syncthreads();
    for (int n = tid; n < NPRED; n += 1024) {
        u64 key = kb[n];
        u32 hi = (u32)(key >> 32);
        if (hi > ORD_BASE) {
            int bt = (int)((hi - ORD_BASE - 1u) >> 12);
            if (bt > T) {
                int slot = atomicAdd(&c1pos, 1);
                arena[slot] = key;
            } else if (bt == T) {
                int s2 = atomicAdd(&sidepos, 1);
                if (s2 < 1024) side[s2] = key;           // >1024 in one bucket: implausible
            }
        }
    }
    __syncthreads();

    // --- phase 4: select R largest from bucket T ---
    if (R > 0) {
        int cntT = sidepos;
        if (cntT <= 256) {
            if (wid == 0) {                              // single-wave in-register sort
                u64 r[4];
#pragma unroll
                for (int e = 0; e < 4; ++e) r[e] = side[4 * lane + e];
                wave_sort256_desc(r);
#pragma unroll
                for (int e = 0; e < 4; ++e) side[4 * lane + e] = r[e];
            }
        } else {                                         // rare fallback: block bitonic 1024
            for (int k = 2; k <= 1024; k <<= 1) {
                for (int j = k >> 1; j >= 1; j >>= 1) {
                    if (tid < 512) {
                        int q = tid;
                        int i = ((q & ~(j - 1)) << 1) | (q & (j - 1));
                        cx_u64(side, i, i | j, (i & k) == 0);
                    }
                    __syncthreads();
                }
            }
        }
        __syncthreads();
        if (tid < R) arena[C1 + tid] = side[tid];        // R <= cntT <= 1024
    }
    __syncthreads();

    // --- phase 5: full sort of top-4096, keep in LDS + write global ---
    {
        u64 r[4];
#pragma unroll
        for (int e = 0; e < 4; ++e) r[e] = arena[4 * tid + e];
        hybrid_sort4096_desc(r, arena);
#pragma unroll
        for (int e = 0; e < 4; ++e) {
            arena[4 * tid + e] = r[e];
            topSorted[(long long)b * TOPK + 4 * tid + e] = r[e];
        }
    }
    __syncthreads();

    // --- phase 6: build boxes/classes/counts; zero keep/gsupp ---
#pragma unroll
    for (int e = 0; e < 4; ++e) {
        int r = e * 1024 + tid;
        u64 key = arena[r];
        u32 hi = (u32)(key >> 32);
        u8 c = 0xFF;
        if (hi > 0x80000000u) {                          // score > 0 (valid)
            int n = 32767 - (int)((key >> 7) & 0x7FFFu);
            int ci = (int)(key & 0x7Fu);
            const float* row = pred + ((long long)b * NPRED + n) * CDIM;
            float x = row[0], y = row[1], w = row[2], hh = row[3];
            float off = (float)ci * MAXWH;
            float4 o;
            o.x = (x - w * 0.5f) + off;
            o.y = (y - hh * 0.5f) + off;
            o.z = (x + w * 0.5f) + off;
            o.w = (y + hh * 0.5f) + off;
            ob[b * 4096 + r] = o;
            c = (u8)ci;
            atomicAdd(&cnt[ci], 1u);
        }
        clsb[r] = c;
        keep[b * 4096 + r] = 0;
        gsupp[b * 4096 + r] = 0;
    }
    __syncthreads();

    // --- phase 7: exclusive prefix of cnt[80] (wave 0) ---
    if (wid == 0) {
        u32 c0 = (lane < NCLS) ? cnt[lane] : 0u;         // lanes 0..63: classes 0..63
        u32 p = c0;
        for (int o = 1; o < 64; o <<= 1) {
            u32 v = __shfl_up(p, o, 64);
            if (lane >= o) p += v;
        }
        startsh[lane] = p - c0;                          // exclusive
        u32 tot64 = __shfl(p, 63, 64);
        u32 c1 = (lane < 16) ? cnt[64 + lane] : 0u;
        u32 p1 = c1;
        for (int o = 1; o < 16; o <<= 1) {
            u32 v = __shfl_up(p1, o, 64);
            if (lane >= o) p1 += v;
        }
        if (lane < 16) startsh[64 + lane] = tot64 + p1 - c1;
    }
    __syncthreads();
    if (tid < NCLS) {
        count[b * NCLS + tid] = cnt[tid];
        startg[b * NCLS + tid] = startsh[tid];
    }

    // --- phase 8: stable per-class gather (wave w: classes w, w+16, ...) ---
    {
        const u64 lt = (1ull << lane) - 1ull;
        for (int q = 0; q < 5; ++q) {
            int c = wid + 16 * q;
            u32 pos = startsh[c];
            for (int it = 0; it < 64; ++it) {
                u8 cc = clsb[it * 64 + lane];
                u64 mm = __ballot(cc == (u8)c);
                if (cc == (u8)c) {
                    int ofs = __popcll(mm & lt);
                    segIdx[b * 4096 + pos + ofs] = (u16)(it * 64 + lane);
                }
                pos += (u32)__popcll(mm);
            }
        }
    }
}

// ---------------- K3n: greedy NMS, one wave per (b,c) ----------------

__global__ __launch_bounds__(64) void k3n_nms(const float4* __restrict__ ob,
                                              const u16* __restrict__ segIdx,
                                              const u32* __restrict__ count,
                                              const u32* __restrict__ startg,
                                              u8* __restrict__ keep,
                                              u8* gsupp_) {
    const int b = blockIdx.x;
    const int c = blockIdx.y;
    const int lane = threadIdx.x;
    const int n = (int)count[b * NCLS + c];
    if (n == 0) return;
    const u32 base = startg[b * NCLS + c];
    __shared__ float4 sbox[1024];
    __shared__ u16 sidx[1024];
    __shared__ u8 ssupp_[1024];
    volatile u8* ssupp = ssupp_;
    volatile u8* gsupp = gsupp_ + b * 4096 + base;       // fallback (n > 1024), pre-zeroed
    const float4* obb = ob + b * 4096;
    const u16* seg = segIdx + b * 4096 + base;

    for (int j = lane; j < n && j < 1024; j += 64) {
        int r = seg[j];
        sidx[j] = (u16)r;
        sbox[j] = obb[r];
        ssupp_[j] = 0;
    }
    __syncthreads();

    {
#pragma clang fp contract(off)
        for (int ii = 0; ii < n; ++ii) {
            bool sup = (ii < 1024) ? (ssupp[ii] != 0) : (gsupp[ii] != 0);
            if (sup) continue;                           // wave-uniform
            int ri = (ii < 1024) ? (int)sidx[ii] : (int)seg[ii];
            if (lane == 0) keep[b * 4096 + ri] = 1;
            float4 bi = (ii < 1024) ? sbox[ii] : obb[seg[ii]];
            float a1 = (bi.z - bi.x) * (bi.w - bi.y);
            for (int jj = ii + 1 + lane; jj < n; jj += 64) {
                float4 bj = (jj < 1024) ? sbox[jj] : obb[seg[jj]];
                float ltx = fmaxf(bi.x, bj.x);
                float lty = fmaxf(bi.y, bj.y);
                float rbx = fminf(bi.z, bj.z);
                float rby = fminf(bi.w, bj.w);
                float ww = fmaxf(rbx - ltx, 0.0f);
                float hh = fmaxf(rby - lty, 0.0f);
                float inter = ww * hh;
                float a2 = (bj.z - bj.x) * (bj.w - bj.y);
                float iou = inter / (((a1 + a2) - inter) + 1e-7f);
                if (iou > IOU_T) {
                    if (jj < 1024) ssupp[jj] = 1; else gsupp[jj] = 1;
                }
            }
            __syncthreads();                             // single-wave: orders LDS supp writes
        }
    }
}

// ---------------- K3o: rank-order compaction + output ----------------

__global__ __launch_bounds__(256) void k3o_out(const float* __restrict__ pred,
                                               const u64* __restrict__ topSorted,
                                               const u8* __restrict__ keep,
                                               float* __restrict__ out) {
    const int b = blockIdx.x;
    const int tid = threadIdx.x;
    __shared__ u64 words[64];
    __shared__ int wpre[64];
    float* outb = out + (long long)b * MAXDET * 6;
    for (int i = tid; i < MAXDET * 6; i += 256) outb[i] = 0.0f;   // d_out is poisoned
    const u8* kp = keep + b * 4096;
    if (tid < 64) {
        u64 w = 0ull;
        const u64* k8 = (const u64*)(kp + tid * 64);
#pragma unroll
        for (int q = 0; q < 8; ++q) {
            u64 v = k8[q];
#pragma unroll
            for (int bb = 0; bb < 8; ++bb)
                if ((v >> (8 * bb)) & 0xFFull) w |= 1ull << (q * 8 + bb);
        }
        words[tid] = w;
    }
    __syncthreads();
    if (tid == 0) {
        int run = 0;
        for (int t = 0; t < 64; ++t) { wpre[t] = run; run += __popcll(words[t]); }
    }
    __syncthreads();
    const u64* kb = topSorted + (long long)b * TOPK;
    for (int r = tid; r < 4096; r += 256) {
        int wd = r >> 6;
        if ((words[wd] >> (r & 63)) & 1ull) {
            int pos = wpre[wd] + __popcll(words[wd] & ((1ull << (r & 63)) - 1ull));
            if (pos < MAXDET) {
                u64 key = kb[r];
                u32 hi = (u32)(key >> 32);
                int n = 32767 - (int)((key >> 7) & 0x7FFFu);
                const float* row = pred + ((long long)b * NPRED + n) * CDIM;
                float x = row[0], y = row[1], w2 = row[2], h = row[3];
                float* o = outb + pos * 6;
                o[0] = x - w2 * 0.5f;
                o[1] = y - h * 0.5f;
                o[2] = x + w2 * 0.5f;
                o[3] = y + h * 0.5f;
                o[4] = __uint_as_float(hi & 0x7FFFFFFFu);   // score
                o[5] = (float)(key & 0x7Fu);                // class (as float)
            }
        }
    }
}

// ---------------- launch ----------------

extern "C" void kernel_launch(void* const* d_in, const int* in_sizes, int n_in,
                              void* d_out, int out_size, void* d_ws, size_t ws_size,
                              hipStream_t stream) {
    const float* pred = (const float*)d_in[0];
    float* out = (float*)d_out;

    char* ws = (char*)d_ws;
    u64* keys      = (u64*)ws;                            // 16*25200*8 = 3,225,600 B
    u64* topSorted = (u64*)(ws + 3225600);                // 16*4096*8  =   524,288 B
    float4* ob     = (float4*)(ws + 3749888);             // 16*4096*16 = 1,048,576 B
    u16* segIdx    = (u16*)(ws + 4798464);                //   131,072 B
    u32* startg    = (u32*)(ws + 4929536);                //     5,120 B
    u32* count     = (u32*)(ws + 4934656);                //     5,120 B
    u8* keep       = (u8*)(ws + 4939776);                 //    65,536 B  [zeroed by k2cs]
    u8* gsupp      = (u8*)(ws + 5005312);                 //    65,536 B  [zeroed by k2cs]

    hipLaunchKernelGGL(k1_score, dim3(BATCH * NPRED / 16), dim3(256), 0, stream, pred, keys);
    hipLaunchKernelGGL(k2cs, dim3(BATCH), dim3(1024), 0, stream,
                       pred, keys, topSorted, ob, segIdx, count, startg, keep, gsupp);
    hipLaunchKernelGGL(k3n_nms, dim3(BATCH, NCLS), dim3(64), 0, stream,
                       ob, segIdx, count, startg, keep, gsupp);
    hipLaunchKernelGGL(k3o_out, dim3(BATCH), dim3(256), 0, stream, pred, topSorted, keep, out);
}